// Round 5
// baseline (68.886 us; speedup 1.0000x reference)
//
#include <hip/hip_runtime.h>
#include <math.h>

// BettingLoss: scalar loss over B=1048576 races, T=8 dogs.
// Inputs (float32, each B*T): predicted_probs, true_winners(one-hot),
// market_odds, gumbel_noise. Output: 1 float32 scalar.
//
// R4: R0's proven main loop (grid-stride, whole race per thread, 1024
// blocks — best replay so far at 36us) + fused finalize via last-block
// atomic ticket. R1-R3 showed: main kernel time is invariant to grid /
// occupancy / load layout (~4.3 TB/s from L3); the replay regressions
// came from the second (finalize) kernel whose serial partial-read grows
// with grid size. So: keep main minimal, delete the second launch.

constexpr int NT = 256;
constexpr int NB = 1024;

__device__ __forceinline__ float fastrcp(float x) {
  return __builtin_amdgcn_rcpf(x);
}

// acc: 0=cnt, 1=sum(ce*valid), 2=sum(ce), 3=sum(soft_ep*valid),
//      4=sum(max_prob), 5=sum(entropy)
__global__ __launch_bounds__(NT, 4) void betting_main(
    const float4* __restrict__ pp4, const float4* __restrict__ tw4,
    const float4* __restrict__ mo4, const float4* __restrict__ gn4,
    float* __restrict__ partials, unsigned* __restrict__ counter,
    float* __restrict__ out, int nraces, int nb) {
  const int tid = blockIdx.x * NT + threadIdx.x;
  const int ntot = gridDim.x * NT;

  float acc[6] = {0.f, 0.f, 0.f, 0.f, 0.f, 0.f};

  for (int r = tid; r < nraces; r += ntot) {
    float4 a0 = pp4[2 * r], a1 = pp4[2 * r + 1];
    float4 b0 = tw4[2 * r], b1 = tw4[2 * r + 1];
    float4 c0 = mo4[2 * r], c1 = mo4[2 * r + 1];
    float4 d0 = gn4[2 * r], d1 = gn4[2 * r + 1];

    float p[8] = {a0.x, a0.y, a0.z, a0.w, a1.x, a1.y, a1.z, a1.w};
    float w[8] = {b0.x, b0.y, b0.z, b0.w, b1.x, b1.y, b1.z, b1.w};
    float o[8] = {c0.x, c0.y, c0.z, c0.w, c1.x, c1.y, c1.z, c1.w};
    float g[8] = {d0.x, d0.y, d0.z, d0.w, d1.x, d1.y, d1.z, d1.w};

    // validity
    bool anypos = false;
    float simp = 0.f;
#pragma unroll
    for (int t = 0; t < 8; ++t) {
      anypos = anypos || (o[t] > 0.f);
      simp += fastrcp(fmaxf(o[t], 1.01f));
    }
    float vf = (anypos && simp >= 0.95f) ? 1.f : 0.f;

    // expected profit (mask only matters through vf-weighted terms)
    float ep[8];
#pragma unroll
    for (int t = 0; t < 8; ++t)
      ep[t] = (o[t] * 1.1f * p[t] - 1.f) * (0.02f * 0.95f) * vf;

    // gumbel-softmax selection: softmax(ep*100 + g*10)
    float z[8], zm = -INFINITY;
#pragma unroll
    for (int t = 0; t < 8; ++t) {
      z[t] = ep[t] * 100.f + g[t] * 10.f;
      zm = fmaxf(zm, z[t]);
    }
    float s2 = 0.f, sp = 0.f;
#pragma unroll
    for (int t = 0; t < 8; ++t) {
      float e = __expf(z[t] - zm);
      s2 += e;
      sp += e * ep[t];
    }
    float soft_ep = sp * fastrcp(s2);

    // cross-entropy (probs as logits), one-hot label
    float m = -INFINITY;
#pragma unroll
    for (int t = 0; t < 8; ++t) m = fmaxf(m, p[t]);
    float se = 0.f, pl = 0.f;
#pragma unroll
    for (int t = 0; t < 8; ++t) {
      se += __expf(p[t] - m);
      pl += w[t] * p[t];
    }
    float ce = m + __logf(se) - pl;

    // entropy
    float ent = 0.f;
#pragma unroll
    for (int t = 0; t < 8; ++t) ent -= p[t] * __logf(p[t] + 1e-8f);

    acc[0] += vf;
    acc[1] += ce * vf;
    acc[2] += ce;
    acc[3] += soft_ep * vf;
    acc[4] += m;
    acc[5] += ent;
  }

  // ---- block reduction ----
  __shared__ float red[NT / 64][6];
#pragma unroll
  for (int k = 0; k < 6; ++k) {
#pragma unroll
    for (int off = 32; off >= 1; off >>= 1) acc[k] += __shfl_down(acc[k], off);
  }
  const int lane = threadIdx.x & 63, wave = threadIdx.x >> 6;
  if (lane == 0) {
#pragma unroll
    for (int k = 0; k < 6; ++k) red[wave][k] = acc[k];
  }
  __syncthreads();

  // ---- publish partials + ticket ----
  __shared__ int slast;
  if (threadIdx.x == 0) {
#pragma unroll
    for (int k = 0; k < 6; ++k) {
      float s = red[0][k] + red[1][k] + red[2][k] + red[3][k];
      __hip_atomic_store(&partials[k * nb + blockIdx.x], s, __ATOMIC_RELAXED,
                         __HIP_MEMORY_SCOPE_AGENT);
    }
    unsigned c = __hip_atomic_fetch_add(counter, 1u, __ATOMIC_ACQ_REL,
                                        __HIP_MEMORY_SCOPE_AGENT);
    slast = (c == (unsigned)(nb - 1));
  }
  __syncthreads();
  if (!slast) return;

  // ---- last block: final reduction in double ----
  __shared__ double redd[NT / 64][6];
  double a[6] = {0, 0, 0, 0, 0, 0};
#pragma unroll
  for (int k = 0; k < 6; ++k)
    for (int i = threadIdx.x; i < nb; i += NT)
      a[k] += (double)__hip_atomic_load(&partials[k * nb + i], __ATOMIC_RELAXED,
                                        __HIP_MEMORY_SCOPE_AGENT);
#pragma unroll
  for (int k = 0; k < 6; ++k) {
#pragma unroll
    for (int off = 32; off >= 1; off >>= 1) a[k] += __shfl_down(a[k], off);
  }
  if (lane == 0) {
#pragma unroll
    for (int k = 0; k < 6; ++k) redd[wave][k] = a[k];
  }
  __syncthreads();
  if (threadIdx.x == 0) {
    const double Bd = (double)nraces;
    double s[6];
#pragma unroll
    for (int k = 0; k < 6; ++k)
      s[k] = redd[0][k] + redd[1][k] + redd[2][k] + redd[3][k];
    double cnt = s[0], Scev = s[1], Sce = s[2], Ssoft = s[3], Smax = s[4],
           Sent = s[5];
    double pred = (cnt > 0.0) ? Scev / fmax(cnt, 1.0) : Sce / Bd;
    double conf = -(Smax / Bd) * 0.1;
    double bet = (cnt > 0.0) ? -Ssoft / Bd : conf;
    double entr = Sent / Bd;
    double lam = fmin(0.5 + cnt / 10000.0 * 0.5, 1.0);
    out[0] = (float)(pred + lam * bet - 0.01 * entr);
  }
}

extern "C" void kernel_launch(void* const* d_in, const int* in_sizes, int n_in,
                              void* d_out, int out_size, void* d_ws,
                              size_t ws_size, hipStream_t stream) {
  const float4* pp = (const float4*)d_in[0];
  const float4* tw = (const float4*)d_in[1];
  const float4* mo = (const float4*)d_in[2];
  const float4* gn = (const float4*)d_in[3];
  float* out = (float*)d_out;

  const int nraces = in_sizes[0] / 8;

  int nb = NB;
  while ((size_t)((6 * nb + 1) * 4) > ws_size && nb > 64) nb >>= 1;

  float* partials = (float*)d_ws;
  unsigned* counter = (unsigned*)(partials + 6 * nb);
  hipMemsetAsync(counter, 0, sizeof(unsigned), stream);

  betting_main<<<nb, NT, 0, stream>>>(pp, tw, mo, gn, partials, counter, out,
                                      nraces, nb);
}

// Round 6
// 35.525 us; speedup vs baseline: 1.9391x; 1.9391x over previous
//
#include <hip/hip_runtime.h>
#include <math.h>

// BettingLoss: scalar loss over B=1048576 races, T=8 dogs.
// Inputs (float32, each B*T): predicted_probs, true_winners(one-hot),
// market_odds, gumbel_noise. Output: 1 float32 scalar.
//
// R5: exact R0 structure (best replay: 36us; two kernels, 1024 blocks,
// SoA partials — fused-atomic finalize regressed 2x in R3/R4, abandoned).
// Single change: sched_barrier(0) between the 8 float4 loads and the
// compute. R0-R4 all show VGPR<=36: the scheduler sinks each load to its
// first use, serializing 8 L3 round-trips per race. The fence pins all 8
// loads before any compute -> per-wave MLP. Discriminates latency-bound
// (time drops) vs per-CU outstanding-request-limit (time flat).

constexpr int T = 8;
constexpr int NB = 1024;
constexpr int NT = 256;

__device__ __forceinline__ float fastrcp(float x) {
  return __builtin_amdgcn_rcpf(x);
}

// acc: 0=cnt, 1=sum(ce*valid), 2=sum(ce), 3=sum(soft_ep*valid),
//      4=sum(max_prob), 5=sum(entropy)
__global__ __launch_bounds__(NT, 4) void betting_main(
    const float4* __restrict__ pp4, const float4* __restrict__ tw4,
    const float4* __restrict__ mo4, const float4* __restrict__ gn4,
    float* __restrict__ partials, int nraces) {
  const int tid = blockIdx.x * NT + threadIdx.x;
  const int ntot = gridDim.x * NT;

  float acc[6] = {0.f, 0.f, 0.f, 0.f, 0.f, 0.f};

  for (int r = tid; r < nraces; r += ntot) {
    // ---- issue all 8 loads; fence forbids sinking them into compute ----
    float4 a0 = pp4[2 * r], a1 = pp4[2 * r + 1];
    float4 b0 = tw4[2 * r], b1 = tw4[2 * r + 1];
    float4 c0 = mo4[2 * r], c1 = mo4[2 * r + 1];
    float4 d0 = gn4[2 * r], d1 = gn4[2 * r + 1];
    __builtin_amdgcn_sched_barrier(0);

    float p[T] = {a0.x, a0.y, a0.z, a0.w, a1.x, a1.y, a1.z, a1.w};
    float w[T] = {b0.x, b0.y, b0.z, b0.w, b1.x, b1.y, b1.z, b1.w};
    float o[T] = {c0.x, c0.y, c0.z, c0.w, c1.x, c1.y, c1.z, c1.w};
    float g[T] = {d0.x, d0.y, d0.z, d0.w, d1.x, d1.y, d1.z, d1.w};

    // validity
    bool anypos = false;
    float simp = 0.f;
#pragma unroll
    for (int t = 0; t < T; ++t) {
      anypos = anypos || (o[t] > 0.f);
      simp += fastrcp(fmaxf(o[t], 1.01f));
    }
    float vf = (anypos && simp >= 0.95f) ? 1.f : 0.f;

    // expected profit (vf-masked; only vf-weighted terms consume it)
    float ep[T];
#pragma unroll
    for (int t = 0; t < T; ++t)
      ep[t] = (o[t] * 1.1f * p[t] - 1.f) * (0.02f * 0.95f) * vf;

    // gumbel-softmax selection: softmax(ep*100 + g*10)
    float z[T], zm = -INFINITY;
#pragma unroll
    for (int t = 0; t < T; ++t) {
      z[t] = ep[t] * 100.f + g[t] * 10.f;
      zm = fmaxf(zm, z[t]);
    }
    float s2 = 0.f, sp = 0.f;
#pragma unroll
    for (int t = 0; t < T; ++t) {
      float e = __expf(z[t] - zm);
      s2 += e;
      sp += e * ep[t];
    }
    float soft_ep = sp * fastrcp(s2);

    // cross-entropy (probs as logits), one-hot label
    float m = -INFINITY;
#pragma unroll
    for (int t = 0; t < T; ++t) m = fmaxf(m, p[t]);
    float se = 0.f, pl = 0.f;
#pragma unroll
    for (int t = 0; t < T; ++t) {
      se += __expf(p[t] - m);
      pl += w[t] * p[t];
    }
    float ce = m + __logf(se) - pl;

    // entropy
    float ent = 0.f;
#pragma unroll
    for (int t = 0; t < T; ++t) ent -= p[t] * __logf(p[t] + 1e-8f);

    acc[0] += vf;
    acc[1] += ce * vf;
    acc[2] += ce;
    acc[3] += soft_ep * vf;
    acc[4] += m;
    acc[5] += ent;
  }

  // ---- block reduction: wave shfl -> LDS -> partials ----
  __shared__ float red[NT / 64][6];
#pragma unroll
  for (int k = 0; k < 6; ++k) {
#pragma unroll
    for (int off = 32; off >= 1; off >>= 1) acc[k] += __shfl_down(acc[k], off);
  }
  int lane = threadIdx.x & 63, wave = threadIdx.x >> 6;
  if (lane == 0) {
#pragma unroll
    for (int k = 0; k < 6; ++k) red[wave][k] = acc[k];
  }
  __syncthreads();
  if (threadIdx.x == 0) {
#pragma unroll
    for (int k = 0; k < 6; ++k) {
      float s = red[0][k] + red[1][k] + red[2][k] + red[3][k];
      partials[k * gridDim.x + blockIdx.x] = s;  // SoA for coalesced finalize
    }
  }
}

__global__ __launch_bounds__(NT) void betting_final(
    const float* __restrict__ partials, int nb, float* __restrict__ out,
    double Bd) {
  __shared__ double red[NT / 64][6];
  double a[6] = {0, 0, 0, 0, 0, 0};
#pragma unroll
  for (int k = 0; k < 6; ++k)
    for (int i = threadIdx.x; i < nb; i += NT) a[k] += (double)partials[k * nb + i];
#pragma unroll
  for (int k = 0; k < 6; ++k) {
#pragma unroll
    for (int off = 32; off >= 1; off >>= 1) a[k] += __shfl_down(a[k], off);
  }
  int lane = threadIdx.x & 63, wave = threadIdx.x >> 6;
  if (lane == 0) {
#pragma unroll
    for (int k = 0; k < 6; ++k) red[wave][k] = a[k];
  }
  __syncthreads();
  if (threadIdx.x == 0) {
    double s[6];
#pragma unroll
    for (int k = 0; k < 6; ++k)
      s[k] = red[0][k] + red[1][k] + red[2][k] + red[3][k];
    double cnt = s[0], Scev = s[1], Sce = s[2], Ssoft = s[3], Smax = s[4],
           Sent = s[5];
    double pred = (cnt > 0.0) ? Scev / fmax(cnt, 1.0) : Sce / Bd;
    double conf = -(Smax / Bd) * 0.1;
    double bet = (cnt > 0.0) ? -Ssoft / Bd : conf;
    double entr = Sent / Bd;
    double lam = fmin(0.5 + cnt / 10000.0 * 0.5, 1.0);
    out[0] = (float)(pred + lam * bet - 0.01 * entr);
  }
}

extern "C" void kernel_launch(void* const* d_in, const int* in_sizes, int n_in,
                              void* d_out, int out_size, void* d_ws,
                              size_t ws_size, hipStream_t stream) {
  const float4* pp = (const float4*)d_in[0];
  const float4* tw = (const float4*)d_in[1];
  const float4* mo = (const float4*)d_in[2];
  const float4* gn = (const float4*)d_in[3];
  float* out = (float*)d_out;
  float* partials = (float*)d_ws;

  const int nraces = in_sizes[0] / T;

  int nb = NB;
  while ((size_t)(6 * nb * 4) > ws_size && nb > 64) nb >>= 1;

  betting_main<<<nb, NT, 0, stream>>>(pp, tw, mo, gn, partials, nraces);
  betting_final<<<1, NT, 0, stream>>>(partials, nb, out, (double)nraces);
}